// Round 5
// baseline (287.625 us; speedup 1.0000x reference)
//
#include <hip/hip_runtime.h>

// StyleBlock B=8, C=512, H=W=64, K=3 — bf16 MFMA implicit-GEMM conv, round 10.
// Base = round 9 (129 us conv; dbuf neutral). Diagnosis: per-tap serial chain
// {issue af global loads (L2 ~250cy) -> ds_reads -> 32 MFMA (~155cy)} with
// setprio breaking scheduling regions (loads can't hoist across MFMA
// clusters), and stage-first vmcnt ordering forcing every af wait to drain
// the stage queue (why dbuf was neutral).
// vs round 9:
//  (1) 18-tap flattened loop with explicit one-tap-ahead af register
//      prefetch (afp[2][4], static indices under full unroll).
//  (2) setprio removed (un-break scheduling regions).
//  (3) stage(ib+1) issued at tt==16 — AFTER all af loads of this ib, so af
//      waits are vmcnt(9)-class and never drain the stage; stage drains only
//      at next ib's pre-barrier vmcnt(0), covered by tap-17 MFMA + slack.

#define CC 512
#define BB 8
#define HWSZ 4096

#define C_STYLE 0.04419417382415922f   // 1/sqrt(512)
#define C_CONV  0.014731391274719739f  // 1/sqrt(512*9)

typedef __attribute__((ext_vector_type(8))) short bf16x8;
typedef __attribute__((ext_vector_type(4))) float f32x4;

static __device__ __forceinline__ short f2bf(float f) {
  unsigned u = __float_as_uint(f);
  unsigned r = (u + 0x7fffu + ((u >> 16) & 1u)) >> 16;  // RNE
  return (short)r;
}

static __device__ __forceinline__ void load_lds_16(const void* g, void* l) {
  __builtin_amdgcn_global_load_lds(
      (const __attribute__((address_space(1))) unsigned int*)g,
      (__attribute__((address_space(3))) unsigned int*)l, 16, 0, 0);
}

// ------------- wprep: cw fp32 -> bf16 A-frags + wsq (fused) -------------
// wfrag idx: (((t*16 + ib32)*32 + ob)*64 + lane)*8 + j
//   o = ob*16 + (lane&15), i = ib32*32 + ((lane>>4)&3)*8 + j
__global__ void wprep_kernel(const float* __restrict__ cw,
                             short* __restrict__ wfrag,
                             float* __restrict__ wsq) {
  int t0 = blockIdx.x * blockDim.x + threadIdx.x;  // [0, 512*512) = o*512+i
  int o = t0 >> 9;
  int i = t0 & 511;
  int ib32 = i >> 5;
  int ob = o >> 4;
  int lane = (o & 15) + (((i >> 3) & 3) << 4);
  int j = i & 7;
  const float* p = cw + (size_t)t0 * 9;
  float s = 0.f;
#pragma unroll
  for (int t = 0; t < 9; ++t) {
    float v = p[t];
    s = fmaf(v, v, s);
    wfrag[((((size_t)t * 16 + ib32) * 32 + ob) * 64 + lane) * 8 + j] = f2bf(v);
  }
  wsq[t0] = s;
}

// ---------------- style -> alpha (wave per (b,j)) ----------------
__global__ void style_alpha_kernel(const float* __restrict__ w,
                                   const float* __restrict__ sw,
                                   const float* __restrict__ sbias,
                                   float* __restrict__ alpha) {
  int wv = (blockIdx.x * blockDim.x + threadIdx.x) >> 6;  // [0, B*C)
  int lane = threadIdx.x & 63;
  int b = wv >> 9;
  int j = wv & 511;
  float acc = 0.f;
  const float* wr = w + b * CC;
  const float* sr = sw + (size_t)j * CC;
#pragma unroll
  for (int k = 0; k < CC; k += 64) acc = fmaf(wr[k + lane], sr[k + lane], acc);
#pragma unroll
  for (int off = 32; off > 0; off >>= 1) acc += __shfl_down(acc, off);
  if (lane == 0) alpha[wv] = C_CONV * fmaf(C_STYLE, acc, sbias[j]);
}

// ---------------- demod (wave per (b,o)) ----------------
__global__ void demod_kernel(const float* __restrict__ alpha,
                             const float* __restrict__ wsq,
                             float* __restrict__ demod) {
  int wv = (blockIdx.x * blockDim.x + threadIdx.x) >> 6;  // [0, B*C)
  int lane = threadIdx.x & 63;
  int b = wv >> 9;
  int o = wv & 511;
  const float* ar = alpha + b * CC;
  const float* qr = wsq + (size_t)o * CC;
  float s = 0.f;
#pragma unroll
  for (int i = 0; i < CC; i += 64) {
    float a = ar[i + lane];
    s = fmaf(a * a, qr[i + lane], s);
  }
#pragma unroll
  for (int off = 32; off > 0; off >>= 1) s += __shfl_down(s, off);
  if (lane == 0) {
    s += 1e-8f;
    float r = rsqrtf(s);
    r = r * fmaf(-0.5f * s * r, r, 1.5f);
    demod[wv] = r;
  }
}

// ------- xprep: xT[b][ic][py 66][px 66][8i] = bf16(alpha*x), halo zero -----
// grid (66 py, 16 icg, 8 b), block 256: icq = tid>>6, px = tid&63
__global__ void xprep_kernel(const float* __restrict__ x,
                             const float* __restrict__ alpha,
                             short* __restrict__ xT) {
  const int py = blockIdx.x;               // 0..65
  const int ic = blockIdx.y * 4 + (threadIdx.x >> 6);
  const int b = blockIdx.z;
  const int px = threadIdx.x & 63;
  bf16x8 v = (bf16x8){0, 0, 0, 0, 0, 0, 0, 0};
  if (py >= 1 && py <= 64) {
    const float* xp = x + (((size_t)b * CC + ic * 8) * HWSZ + (py - 1) * 64 + px);
    const float* al = alpha + b * CC + ic * 8;
#pragma unroll
    for (int j = 0; j < 8; ++j) v[j] = f2bf(xp[(size_t)j * HWSZ] * al[j]);
  }
  short* row = xT + (((size_t)(b * 64 + ic) * 66 + py) * 66) * 8;
  *(bf16x8*)(row + (px + 1) * 8) = v;
  bf16x8 z = (bf16x8){0, 0, 0, 0, 0, 0, 0, 0};
  if (px == 0) *(bf16x8*)(row) = z;
  if (px == 63) *(bf16x8*)(row + 65 * 8) = z;
}

// ---------------- conv: MFMA implicit GEMM ----------------
// grid 512 blocks, 256 threads = 4 waves, each wave owns 64 o x 128 px.
// Block tile: 256 o x (2 rows x 64 px). K-loop: 8 ibs of 64 i, 18 taps each.
// LDS: 2 x chunks [kc 8][r 4][c 66] x 16B = 2 x 33792 B (double-buffered).
// Swizzle: XCD = lin%8 (hw round-robin); G = XCD parity so each XCD's L2
// only caches one 2.36 MB half of wfrag (L2-resident A stream).
#define NCHUNK 2112
__global__ __launch_bounds__(256, 2) void conv_kernel(
    const short* __restrict__ xT,
    const short* __restrict__ wfrag,
    const float* __restrict__ noise,
    const float* __restrict__ bias,
    const float* __restrict__ scale_noise,
    const float* __restrict__ demod,
    float* __restrict__ out) {
  __shared__ __align__(16) short xs[2 * NCHUNK * 8];

  const int lin = blockIdx.x + 32 * blockIdx.y + 64 * blockIdx.z;
  const int xcd = lin & 7;                  // assumed hw XCD = lin % 8
  const int j = lin >> 3;                   // 0..63, per-XCD block sequence
  const int G = xcd & 1;                    // 256-o group, constant per XCD
  const int b = (xcd >> 1) + 4 * (j & 1);   // 2 b-values per XCD
  const int y0 = (j >> 1) * 2;              // first output row (0..62 even)
  const int tid = threadIdx.x;
  const int lane = tid & 63;
  const int wave = tid >> 6;                // owns o in [G*256+wave*64, +64)
  const int n = lane & 15;
  const int quad = lane >> 4;

  f32x4 acc[4][8];                          // [p (16-o frag)][q (row*4+colblk)]
#pragma unroll
  for (int p = 0; p < 4; ++p)
#pragma unroll
    for (int q = 0; q < 8; ++q) acc[p][q] = (f32x4){0.f, 0.f, 0.f, 0.f};

  // staging descriptors: chunk cid = (kc*4 + r)*66 + c  ->  global chunk
  // g = ((b*64 + ib*8 + kc)*66 + (y0+r))*66 + c ; per-ib advance 8*66*66 chunks
  const char* xTb = (const char*)xT;
  unsigned goff[9];
#pragma unroll
  for (int it = 0; it < 9; ++it) {
    int cid = tid + it * 256;
    int kc = cid / 264;
    int rem = cid - kc * 264;
    int r = rem / 66;
    int c = rem - r * 66;
    goff[it] = (unsigned)((((b * 64 + kc) * 66 + (y0 + r)) * 66 + c) * 16);
  }

  // A base for this wave's 64-o slice: ob = G*16 + wave*4 + p
  const short* wf0 = wfrag + ((size_t)((G * 16 + wave * 4) * 64 + lane)) * 8;

  // prologue: stage tile 0 into buffer half 0
#pragma unroll
  for (int it = 0; it < 9; ++it) {
    int cid = tid + it * 256;
    if (cid < NCHUNK) load_lds_16(xTb + goff[it], xs + (size_t)cid * 8);
    goff[it] += 8 * 66 * 66 * 16;
  }

  for (int ib = 0; ib < 8; ++ib) {
    const int sel = ib & 1;
    asm volatile("s_waitcnt vmcnt(0)" ::: "memory");
    __builtin_amdgcn_s_barrier();
    const short* cxs = xs + (size_t)sel * NCHUNK * 8;

    // af register pipeline: afp[cu] = current tap, afp[cu^1] = prefetch
    bf16x8 afp[2][4];
    {
      const short* wp = wf0 + (size_t)(0 * 16 + ib * 2) * 16384;  // tt=0
#pragma unroll
      for (int p = 0; p < 4; ++p) afp[0][p] = *(const bf16x8*)(wp + p * 512);
    }

#pragma unroll
    for (int tt = 0; tt < 18; ++tt) {
      const int cu = tt & 1;
      const int kstep = tt / 9;
      const int t = tt - kstep * 9;
      const int dy = t / 3 - 1;
      const int dx = t % 3 - 1;
      // prefetch af for tap tt+1 (issued before this tap's MFMAs)
      if (tt < 17) {
        const int ks2 = (tt + 1) / 9;
        const int t2 = (tt + 1) - ks2 * 9;
        const short* wp2 =
            wf0 + (size_t)(t2 * 16 + ib * 2 + ks2) * 16384;
#pragma unroll
        for (int p = 0; p < 4; ++p)
          afp[cu ^ 1][p] = *(const bf16x8*)(wp2 + p * 512);
      }
      const short* bp =
          cxs + (((kstep * 4 + quad) * 4 + dy + 1) * 66 + 1 + n + dx) * 8;
      bf16x8 bfv[8];
#pragma unroll
      for (int q = 0; q < 8; ++q)
        bfv[q] = *(const bf16x8*)(bp + ((q >> 2) * 66 + (q & 3) * 16) * 8);
#pragma unroll
      for (int p = 0; p < 4; ++p)
#pragma unroll
        for (int q = 0; q < 8; ++q)
          acc[p][q] = __builtin_amdgcn_mfma_f32_16x16x32_bf16(
              afp[cu][p], bfv[q], acc[p][q], 0, 0, 0);
      // stage next ib AFTER all this ib's af loads are issued (tt==16), so
      // af vmcnt waits never have to drain the stage queue
      if (tt == 16 && ib < 7) {
#pragma unroll
        for (int it = 0; it < 9; ++it) {
          int cid = tid + it * 256;
          if (cid < NCHUNK)
            load_lds_16(xTb + goff[it],
                        xs + (size_t)((sel ^ 1) * NCHUNK + cid) * 8);
          goff[it] += 8 * 66 * 66 * 16;
        }
      }
    }
  }

  // epilogue: demod, noise, bias, leaky
  const float sn = scale_noise[0];
#pragma unroll
  for (int q = 0; q < 8; ++q) {
    const int y = y0 + (q >> 2);
    const int col = (q & 3) * 16 + n;
    const float nz = sn * noise[b * HWSZ + y * 64 + col];
#pragma unroll
    for (int p = 0; p < 4; ++p) {
      const int o0 = G * 256 + wave * 64 + p * 16 + quad * 4;
#pragma unroll
      for (int r = 0; r < 4; ++r) {
        const int o = o0 + r;
        float v = fmaf(acc[p][q][r], demod[b * CC + o], nz + bias[o]);
        out[((size_t)(b * CC + o)) * HWSZ + y * 64 + col] =
            v > 0.f ? v : 0.2f * v;
      }
    }
  }
}

extern "C" void kernel_launch(void* const* d_in, const int* in_sizes, int n_in,
                              void* d_out, int out_size, void* d_ws, size_t ws_size,
                              hipStream_t stream) {
  const float* x     = (const float*)d_in[0];
  const float* w     = (const float*)d_in[1];
  const float* noise = (const float*)d_in[2];
  const float* cw    = (const float*)d_in[3];
  const float* sw    = (const float*)d_in[4];
  const float* sbias = (const float*)d_in[5];
  const float* bias  = (const float*)d_in[6];
  const float* sn    = (const float*)d_in[7];
  float* out = (float*)d_out;

  float* alpha = (float*)d_ws;                        // 4096 f
  float* demod = alpha + BB * CC;                     // 4096 f
  float* wsq   = demod + BB * CC;                     // 262144 f
  short* wfrag = (short*)(wsq + CC * CC);             // 9*16*32*64*8 = 2359296 bf16
  short* xT    = wfrag + (size_t)9 * 16 * 32 * 64 * 8;  // 8*64*66*66*8 bf16

  style_alpha_kernel<<<dim3(BB * CC / 4), 256, 0, stream>>>(w, sw, sbias, alpha);
  wprep_kernel<<<dim3((CC * CC) / 256), 256, 0, stream>>>(cw, wfrag, wsq);
  demod_kernel<<<dim3(BB * CC / 4), 256, 0, stream>>>(alpha, wsq, demod);
  xprep_kernel<<<dim3(66, 16, BB), 256, 0, stream>>>(x, alpha, xT);
  conv_kernel<<<dim3(32, 2, BB), 256, 0, stream>>>(
      xT, wfrag, noise, bias, sn, demod, out);
}

// Round 6
// 249.778 us; speedup vs baseline: 1.1515x; 1.1515x over previous
//
#include <hip/hip_runtime.h>

// StyleBlock B=8, C=512, H=W=64, K=3 — bf16 MFMA implicit-GEMM conv, round 11.
// conv = round-6 verbatim (129 us, best; r7/r8/r10 micro-scheduling all
// regressed, r9 dbuf neutral -> r6 is the stable plateau).
// NEW: prep fused 5 -> 3 launches along the dependency cut:
//   A: style_alpha || wprep   (mutually independent)
//   B: demod || xprep         (both depend only on A's outputs)
//   C: conv
// Total non-conv time has been ~120-126 us every round vs ~30 us of ideal
// memory traffic — this round isolates launch-gap overhead from prep
// internals (pure block-range fusion, per-thread code identical).

#define CC 512
#define BB 8
#define HWSZ 4096

#define C_STYLE 0.04419417382415922f   // 1/sqrt(512)
#define C_CONV  0.014731391274719739f  // 1/sqrt(512*9)

typedef __attribute__((ext_vector_type(8))) short bf16x8;
typedef __attribute__((ext_vector_type(4))) float f32x4;

static __device__ __forceinline__ short f2bf(float f) {
  unsigned u = __float_as_uint(f);
  unsigned r = (u + 0x7fffu + ((u >> 16) & 1u)) >> 16;  // RNE
  return (short)r;
}

static __device__ __forceinline__ void load_lds_16(const void* g, void* l) {
  __builtin_amdgcn_global_load_lds(
      (const __attribute__((address_space(1))) unsigned int*)g,
      (__attribute__((address_space(3))) unsigned int*)l, 16, 0, 0);
}

// ---------------- prep A: style_alpha (blocks 0..1023) || wprep (1024..2047)
// style_alpha: wave per (b,j): alpha[b*512+j] = c_conv*(c_style*<w_b, sw_j> + sbias_j)
// wprep: thread per (o,i): 9 taps -> wfrag bf16 + wsq = sum cw^2
// wfrag idx: (((t*16 + ib32)*32 + ob)*64 + lane)*8 + jj
//   o = ob*16 + (lane&15), i = ib32*32 + ((lane>>4)&3)*8 + jj
__global__ void prepA_kernel(const float* __restrict__ w,
                             const float* __restrict__ sw,
                             const float* __restrict__ sbias,
                             float* __restrict__ alpha,
                             const float* __restrict__ cw,
                             short* __restrict__ wfrag,
                             float* __restrict__ wsq) {
  if (blockIdx.x < 1024) {
    int wv = (blockIdx.x * blockDim.x + threadIdx.x) >> 6;  // [0, B*C)
    int lane = threadIdx.x & 63;
    int b = wv >> 9;
    int j = wv & 511;
    float acc = 0.f;
    const float* wr = w + b * CC;
    const float* sr = sw + (size_t)j * CC;
#pragma unroll
    for (int k = 0; k < CC; k += 64) acc = fmaf(wr[k + lane], sr[k + lane], acc);
#pragma unroll
    for (int off = 32; off > 0; off >>= 1) acc += __shfl_down(acc, off);
    if (lane == 0) alpha[wv] = C_CONV * fmaf(C_STYLE, acc, sbias[j]);
  } else {
    int t0 = (blockIdx.x - 1024) * blockDim.x + threadIdx.x;  // o*512+i
    int o = t0 >> 9;
    int i = t0 & 511;
    int ib32 = i >> 5;
    int ob = o >> 4;
    int lane = (o & 15) + (((i >> 3) & 3) << 4);
    int jj = i & 7;
    const float* p = cw + (size_t)t0 * 9;
    float s = 0.f;
#pragma unroll
    for (int t = 0; t < 9; ++t) {
      float v = p[t];
      s = fmaf(v, v, s);
      wfrag[((((size_t)t * 16 + ib32) * 32 + ob) * 64 + lane) * 8 + jj] = f2bf(v);
    }
    wsq[t0] = s;
  }
}

// ---------------- prep B: demod (blocks 0..1023) || xprep (1024..10471)
// demod: wave per (b,o): rsqrt(sum_i alpha^2 * wsq + eps)
// xprep: xT[b][ic][py 66][px 66][8i] = bf16(alpha*x), halo zero
__global__ void prepB_kernel(const float* __restrict__ alpha,
                             const float* __restrict__ wsq,
                             float* __restrict__ demod,
                             const float* __restrict__ x,
                             short* __restrict__ xT) {
  if (blockIdx.x < 1024) {
    int wv = (blockIdx.x * blockDim.x + threadIdx.x) >> 6;  // [0, B*C)
    int lane = threadIdx.x & 63;
    int b = wv >> 9;
    int o = wv & 511;
    const float* ar = alpha + b * CC;
    const float* qr = wsq + (size_t)o * CC;
    float s = 0.f;
#pragma unroll
    for (int i = 0; i < CC; i += 64) {
      float a = ar[i + lane];
      s = fmaf(a * a, qr[i + lane], s);
    }
#pragma unroll
    for (int off = 32; off > 0; off >>= 1) s += __shfl_down(s, off);
    if (lane == 0) {
      s += 1e-8f;
      float r = rsqrtf(s);
      r = r * fmaf(-0.5f * s * r, r, 1.5f);
      demod[wv] = r;
    }
  } else {
    const int id = blockIdx.x - 1024;       // (py,icg,b): py fastest
    const int py = id % 66;                 // 0..65
    const int rem = id / 66;
    const int icg = rem & 15;
    const int b = rem >> 4;
    const int ic = icg * 4 + (threadIdx.x >> 6);
    const int px = threadIdx.x & 63;
    bf16x8 v = (bf16x8){0, 0, 0, 0, 0, 0, 0, 0};
    if (py >= 1 && py <= 64) {
      const float* xp =
          x + (((size_t)b * CC + ic * 8) * HWSZ + (py - 1) * 64 + px);
      const float* al = alpha + b * CC + ic * 8;
#pragma unroll
      for (int j = 0; j < 8; ++j) v[j] = f2bf(xp[(size_t)j * HWSZ] * al[j]);
    }
    short* row = xT + (((size_t)(b * 64 + ic) * 66 + py) * 66) * 8;
    *(bf16x8*)(row + (px + 1) * 8) = v;
    bf16x8 z = (bf16x8){0, 0, 0, 0, 0, 0, 0, 0};
    if (px == 0) *(bf16x8*)(row) = z;
    if (px == 63) *(bf16x8*)(row + 65 * 8) = z;
  }
}

// ---------------- conv: MFMA implicit GEMM (round-6 verbatim) ----------------
// grid 512 blocks, 256 threads = 4 waves, each wave owns 64 o x 128 px.
// Block tile: 256 o x (2 rows x 64 px). K-loop: 8 ibs of 64 i.
// LDS: chunks [kc 8][r 4][c 66] x 16B = 33792 B (2112 chunks).
// Swizzle: XCD = lin%8 (hw round-robin); G = XCD parity so each XCD's L2
// only caches one 2.36 MB half of wfrag (L2-resident A stream).
#define NCHUNK 2112
__global__ __launch_bounds__(256, 2) void conv_kernel(
    const short* __restrict__ xT,
    const short* __restrict__ wfrag,
    const float* __restrict__ noise,
    const float* __restrict__ bias,
    const float* __restrict__ scale_noise,
    const float* __restrict__ demod,
    float* __restrict__ out) {
  __shared__ __align__(16) short xs[NCHUNK * 8];

  const int lin = blockIdx.x + 32 * blockIdx.y + 64 * blockIdx.z;
  const int xcd = lin & 7;                  // assumed hw XCD = lin % 8
  const int j = lin >> 3;                   // 0..63, per-XCD block sequence
  const int G = xcd & 1;                    // 256-o group, constant per XCD
  const int b = (xcd >> 1) + 4 * (j & 1);   // 2 b-values per XCD
  const int y0 = (j >> 1) * 2;              // first output row (0..62 even)
  const int tid = threadIdx.x;
  const int lane = tid & 63;
  const int wave = tid >> 6;                // owns o in [G*256+wave*64, +64)
  const int n = lane & 15;
  const int quad = lane >> 4;

  f32x4 acc[4][8];                          // [p (16-o frag)][q (row*4+colblk)]
#pragma unroll
  for (int p = 0; p < 4; ++p)
#pragma unroll
    for (int q = 0; q < 8; ++q) acc[p][q] = (f32x4){0.f, 0.f, 0.f, 0.f};

  // staging descriptors: chunk cid = (kc*4 + r)*66 + c  ->  global chunk
  // g = ((b*64 + ib*8 + kc)*66 + (y0+r))*66 + c ; per-ib advance 8*66*66 chunks
  const char* xTb = (const char*)xT;
  unsigned goff[9];
#pragma unroll
  for (int it = 0; it < 9; ++it) {
    int cid = tid + it * 256;
    int kc = cid / 264;
    int rem = cid - kc * 264;
    int r = rem / 66;
    int c = rem - r * 66;
    goff[it] = (unsigned)((((b * 64 + kc) * 66 + (y0 + r)) * 66 + c) * 16);
  }

  // A base for this wave's 64-o slice: ob = G*16 + wave*4 + p
  const short* wf0 = wfrag + ((size_t)((G * 16 + wave * 4) * 64 + lane)) * 8;

  for (int ib = 0; ib < 8; ++ib) {
    __syncthreads();
#pragma unroll
    for (int it = 0; it < 9; ++it) {
      int cid = tid + it * 256;
      if (cid < NCHUNK)
        load_lds_16(xTb + goff[it], xs + (size_t)cid * 8);
      goff[it] += 8 * 66 * 66 * 16;
    }
    __syncthreads();

#pragma unroll
    for (int kstep = 0; kstep < 2; ++kstep) {
      const int ib32 = ib * 2 + kstep;
#pragma unroll
      for (int t = 0; t < 9; ++t) {
        const int dy = t / 3 - 1;
        const int dx = t % 3 - 1;
        const short* wp = wf0 + (size_t)(t * 16 + ib32) * 16384;
        bf16x8 af[4];
#pragma unroll
        for (int p = 0; p < 4; ++p)
          af[p] = *(const bf16x8*)(wp + p * 512);
        const short* bp =
            xs + (((kstep * 4 + quad) * 4 + dy + 1) * 66 + 1 + n + dx) * 8;
        bf16x8 bf[8];
#pragma unroll
        for (int q = 0; q < 8; ++q)
          bf[q] = *(const bf16x8*)(bp + ((q >> 2) * 66 + (q & 3) * 16) * 8);
        __builtin_amdgcn_s_setprio(1);
#pragma unroll
        for (int p = 0; p < 4; ++p)
#pragma unroll
          for (int q = 0; q < 8; ++q)
            acc[p][q] = __builtin_amdgcn_mfma_f32_16x16x32_bf16(
                af[p], bf[q], acc[p][q], 0, 0, 0);
        __builtin_amdgcn_s_setprio(0);
      }
    }
  }

  // epilogue: demod, noise, bias, leaky
  const float sn = scale_noise[0];
#pragma unroll
  for (int q = 0; q < 8; ++q) {
    const int y = y0 + (q >> 2);
    const int col = (q & 3) * 16 + n;
    const float nz = sn * noise[b * HWSZ + y * 64 + col];
#pragma unroll
    for (int p = 0; p < 4; ++p) {
      const int o0 = G * 256 + wave * 64 + p * 16 + quad * 4;
#pragma unroll
      for (int r = 0; r < 4; ++r) {
        const int o = o0 + r;
        float v = fmaf(acc[p][q][r], demod[b * CC + o], nz + bias[o]);
        out[((size_t)(b * CC + o)) * HWSZ + y * 64 + col] =
            v > 0.f ? v : 0.2f * v;
      }
    }
  }
}

extern "C" void kernel_launch(void* const* d_in, const int* in_sizes, int n_in,
                              void* d_out, int out_size, void* d_ws, size_t ws_size,
                              hipStream_t stream) {
  const float* x     = (const float*)d_in[0];
  const float* w     = (const float*)d_in[1];
  const float* noise = (const float*)d_in[2];
  const float* cw    = (const float*)d_in[3];
  const float* sw    = (const float*)d_in[4];
  const float* sbias = (const float*)d_in[5];
  const float* bias  = (const float*)d_in[6];
  const float* sn    = (const float*)d_in[7];
  float* out = (float*)d_out;

  float* alpha = (float*)d_ws;                        // 4096 f
  float* demod = alpha + BB * CC;                     // 4096 f
  float* wsq   = demod + BB * CC;                     // 262144 f
  short* wfrag = (short*)(wsq + CC * CC);             // 9*16*32*64*8 = 2359296 bf16
  short* xT    = wfrag + (size_t)9 * 16 * 32 * 64 * 8;  // 8*64*66*66*8 bf16

  prepA_kernel<<<dim3(1024 + (CC * CC) / 256), 256, 0, stream>>>(
      w, sw, sbias, alpha, cw, wfrag, wsq);
  prepB_kernel<<<dim3(1024 + 66 * 16 * BB), 256, 0, stream>>>(
      alpha, wsq, demod, x, xT);
  conv_kernel<<<dim3(32, 2, BB), 256, 0, stream>>>(
      xT, wfrag, noise, bias, sn, demod, out);
}

// Round 7
// 248.334 us; speedup vs baseline: 1.1582x; 1.0058x over previous
//
#include <hip/hip_runtime.h>

// StyleBlock B=8, C=512, H=W=64, K=3 — bf16 MFMA implicit-GEMM conv, round 12.
// conv = round-6 verbatim (129 us plateau; r7/r8/r10 restructures regressed,
// r9 dbuf neutral). r11 fused prep 5->3 launches (-5 us) -> launch gaps
// exonerated; non-conv ~115 us is INSIDE prep.
// vs round 11: wprep rewritten as LDS transpose. Old wprep scattered 9 x 2B
// stores per thread across the frag layout (2.36M scattered stores, ~8
// transactions per wave-store). New: block per (ob, ib32) tile reads 16
// o-rows x 288 contiguous floats coalesced into LDS (18.4 KB), then emits
// wsq (coalesced) + wfrag in layout order: short2 per thread at 2*tid ->
// 256 B/wave contiguous stores, 9 per thread. LDS residues stride-9
// (coprime 32) -> no systematic bank conflict.

#define CC 512
#define BB 8
#define HWSZ 4096

#define C_STYLE 0.04419417382415922f   // 1/sqrt(512)
#define C_CONV  0.014731391274719739f  // 1/sqrt(512*9)

typedef __attribute__((ext_vector_type(8))) short bf16x8;
typedef __attribute__((ext_vector_type(4))) float f32x4;

static __device__ __forceinline__ short f2bf(float f) {
  unsigned u = __float_as_uint(f);
  unsigned r = (u + 0x7fffu + ((u >> 16) & 1u)) >> 16;  // RNE
  return (short)r;
}

static __device__ __forceinline__ void load_lds_16(const void* g, void* l) {
  __builtin_amdgcn_global_load_lds(
      (const __attribute__((address_space(1))) unsigned int*)g,
      (__attribute__((address_space(3))) unsigned int*)l, 16, 0, 0);
}

// ---------------- prep A ----------------
// blocks 0..1023:   style_alpha — wave per (b,j)
// blocks 1024..1535: wprep LDS-transpose — block per (ob 32, ib32 16) tile
// wfrag idx: (((t*16 + ib32)*32 + ob)*64 + lane)*8 + jj
//   o = ob*16 + (lane&15), i = ib32*32 + ((lane>>4)&3)*8 + jj
__global__ __launch_bounds__(256) void prepA_kernel(
    const float* __restrict__ w,
    const float* __restrict__ sw,
    const float* __restrict__ sbias,
    float* __restrict__ alpha,
    const float* __restrict__ cw,
    short* __restrict__ wfrag,
    float* __restrict__ wsq) {
  __shared__ float lds[16][288];             // used by wprep branch only
  if (blockIdx.x < 1024) {
    int wv = (blockIdx.x * blockDim.x + threadIdx.x) >> 6;  // [0, B*C)
    int lane = threadIdx.x & 63;
    int b = wv >> 9;
    int j = wv & 511;
    float acc = 0.f;
    const float* wr = w + b * CC;
    const float* sr = sw + (size_t)j * CC;
#pragma unroll
    for (int k = 0; k < CC; k += 64) acc = fmaf(wr[k + lane], sr[k + lane], acc);
#pragma unroll
    for (int off = 32; off > 0; off >>= 1) acc += __shfl_down(acc, off);
    if (lane == 0) alpha[wv] = C_CONV * fmaf(C_STYLE, acc, sbias[j]);
  } else {
    const int bid = blockIdx.x - 1024;       // 0..511
    const int ob = bid & 31;
    const int ib32 = bid >> 5;               // 0..15
    const int tid = threadIdx.x;
    const int o0 = ob * 16;
    // read phase: 16 rows x 288 contiguous floats (cw[o][i0..i0+32][0..9])
    const float* src = cw + (size_t)o0 * 4608 + ib32 * 288;
#pragma unroll
    for (int k = 0; k < 18; ++k) {
      int idx = k * 256 + tid;
      int row = idx / 288;
      int col = idx - row * 288;
      lds[row][col] = src[(size_t)row * 4608 + col];
    }
    __syncthreads();
    // wsq: 512 (row, il) pairs, 2 per thread
#pragma unroll
    for (int pp = 0; pp < 2; ++pp) {
      int p = pp * 256 + tid;
      int row = p >> 5;
      int il = p & 31;
      float s = 0.f;
#pragma unroll
      for (int t9 = 0; t9 < 9; ++t9) {
        float v = lds[row][il * 9 + t9];
        s = fmaf(v, v, s);
      }
      wsq[(size_t)(o0 + row) * 512 + ib32 * 32 + il] = s;
    }
    // wfrag: per tap t, block's 512 shorts contiguous; short2 at 2*tid
    const int lane = tid >> 2;               // 0..63
    const int jj = (tid & 3) * 2;            // 0,2,4,6
    const int row = lane & 15;
    const int ilb = ((lane >> 4) & 3) * 8 + jj;
    short* dst = wfrag + ((size_t)ib32 * 32 + ob) * 512 + tid * 2;
#pragma unroll
    for (int t9 = 0; t9 < 9; ++t9) {
      short2 v;
      v.x = f2bf(lds[row][ilb * 9 + t9]);
      v.y = f2bf(lds[row][(ilb + 1) * 9 + t9]);
      *(short2*)(dst + (size_t)t9 * 16 * 32 * 512) = v;
    }
  }
}

// ---------------- prep B: demod (blocks 0..1023) || xprep (1024..10471)
// demod: wave per (b,o): rsqrt(sum_i alpha^2 * wsq + eps)
// xprep: xT[b][ic][py 66][px 66][8i] = bf16(alpha*x), halo zero
__global__ void prepB_kernel(const float* __restrict__ alpha,
                             const float* __restrict__ wsq,
                             float* __restrict__ demod,
                             const float* __restrict__ x,
                             short* __restrict__ xT) {
  if (blockIdx.x < 1024) {
    int wv = (blockIdx.x * blockDim.x + threadIdx.x) >> 6;  // [0, B*C)
    int lane = threadIdx.x & 63;
    int b = wv >> 9;
    int o = wv & 511;
    const float* ar = alpha + b * CC;
    const float* qr = wsq + (size_t)o * CC;
    float s = 0.f;
#pragma unroll
    for (int i = 0; i < CC; i += 64) {
      float a = ar[i + lane];
      s = fmaf(a * a, qr[i + lane], s);
    }
#pragma unroll
    for (int off = 32; off > 0; off >>= 1) s += __shfl_down(s, off);
    if (lane == 0) {
      s += 1e-8f;
      float r = rsqrtf(s);
      r = r * fmaf(-0.5f * s * r, r, 1.5f);
      demod[wv] = r;
    }
  } else {
    const int id = blockIdx.x - 1024;       // (py,icg,b): py fastest
    const int py = id % 66;                 // 0..65
    const int rem = id / 66;
    const int icg = rem & 15;
    const int b = rem >> 4;
    const int ic = icg * 4 + (threadIdx.x >> 6);
    const int px = threadIdx.x & 63;
    bf16x8 v = (bf16x8){0, 0, 0, 0, 0, 0, 0, 0};
    if (py >= 1 && py <= 64) {
      const float* xp =
          x + (((size_t)b * CC + ic * 8) * HWSZ + (py - 1) * 64 + px);
      const float* al = alpha + b * CC + ic * 8;
#pragma unroll
      for (int j = 0; j < 8; ++j) v[j] = f2bf(xp[(size_t)j * HWSZ] * al[j]);
    }
    short* row = xT + (((size_t)(b * 64 + ic) * 66 + py) * 66) * 8;
    *(bf16x8*)(row + (px + 1) * 8) = v;
    bf16x8 z = (bf16x8){0, 0, 0, 0, 0, 0, 0, 0};
    if (px == 0) *(bf16x8*)(row) = z;
    if (px == 63) *(bf16x8*)(row + 65 * 8) = z;
  }
}

// ---------------- conv: MFMA implicit GEMM (round-6 verbatim) ----------------
// grid 512 blocks, 256 threads = 4 waves, each wave owns 64 o x 128 px.
// Block tile: 256 o x (2 rows x 64 px). K-loop: 8 ibs of 64 i.
// LDS: chunks [kc 8][r 4][c 66] x 16B = 33792 B (2112 chunks).
// Swizzle: XCD = lin%8 (hw round-robin); G = XCD parity so each XCD's L2
// only caches one 2.36 MB half of wfrag (L2-resident A stream).
#define NCHUNK 2112
__global__ __launch_bounds__(256, 2) void conv_kernel(
    const short* __restrict__ xT,
    const short* __restrict__ wfrag,
    const float* __restrict__ noise,
    const float* __restrict__ bias,
    const float* __restrict__ scale_noise,
    const float* __restrict__ demod,
    float* __restrict__ out) {
  __shared__ __align__(16) short xs[NCHUNK * 8];

  const int lin = blockIdx.x + 32 * blockIdx.y + 64 * blockIdx.z;
  const int xcd = lin & 7;                  // assumed hw XCD = lin % 8
  const int j = lin >> 3;                   // 0..63, per-XCD block sequence
  const int G = xcd & 1;                    // 256-o group, constant per XCD
  const int b = (xcd >> 1) + 4 * (j & 1);   // 2 b-values per XCD
  const int y0 = (j >> 1) * 2;              // first output row (0..62 even)
  const int tid = threadIdx.x;
  const int lane = tid & 63;
  const int wave = tid >> 6;                // owns o in [G*256+wave*64, +64)
  const int n = lane & 15;
  const int quad = lane >> 4;

  f32x4 acc[4][8];                          // [p (16-o frag)][q (row*4+colblk)]
#pragma unroll
  for (int p = 0; p < 4; ++p)
#pragma unroll
    for (int q = 0; q < 8; ++q) acc[p][q] = (f32x4){0.f, 0.f, 0.f, 0.f};

  // staging descriptors: chunk cid = (kc*4 + r)*66 + c  ->  global chunk
  // g = ((b*64 + ib*8 + kc)*66 + (y0+r))*66 + c ; per-ib advance 8*66*66 chunks
  const char* xTb = (const char*)xT;
  unsigned goff[9];
#pragma unroll
  for (int it = 0; it < 9; ++it) {
    int cid = tid + it * 256;
    int kc = cid / 264;
    int rem = cid - kc * 264;
    int r = rem / 66;
    int c = rem - r * 66;
    goff[it] = (unsigned)((((b * 64 + kc) * 66 + (y0 + r)) * 66 + c) * 16);
  }

  // A base for this wave's 64-o slice: ob = G*16 + wave*4 + p
  const short* wf0 = wfrag + ((size_t)((G * 16 + wave * 4) * 64 + lane)) * 8;

  for (int ib = 0; ib < 8; ++ib) {
    __syncthreads();
#pragma unroll
    for (int it = 0; it < 9; ++it) {
      int cid = tid + it * 256;
      if (cid < NCHUNK)
        load_lds_16(xTb + goff[it], xs + (size_t)cid * 8);
      goff[it] += 8 * 66 * 66 * 16;
    }
    __syncthreads();

#pragma unroll
    for (int kstep = 0; kstep < 2; ++kstep) {
      const int ib32 = ib * 2 + kstep;
#pragma unroll
      for (int t = 0; t < 9; ++t) {
        const int dy = t / 3 - 1;
        const int dx = t % 3 - 1;
        const short* wp = wf0 + (size_t)(t * 16 + ib32) * 16384;
        bf16x8 af[4];
#pragma unroll
        for (int p = 0; p < 4; ++p)
          af[p] = *(const bf16x8*)(wp + p * 512);
        const short* bp =
            xs + (((kstep * 4 + quad) * 4 + dy + 1) * 66 + 1 + n + dx) * 8;
        bf16x8 bf[8];
#pragma unroll
        for (int q = 0; q < 8; ++q)
          bf[q] = *(const bf16x8*)(bp + ((q >> 2) * 66 + (q & 3) * 16) * 8);
        __builtin_amdgcn_s_setprio(1);
#pragma unroll
        for (int p = 0; p < 4; ++p)
#pragma unroll
          for (int q = 0; q < 8; ++q)
            acc[p][q] = __builtin_amdgcn_mfma_f32_16x16x32_bf16(
                af[p], bf[q], acc[p][q], 0, 0, 0);
        __builtin_amdgcn_s_setprio(0);
      }
    }
  }

  // epilogue: demod, noise, bias, leaky
  const float sn = scale_noise[0];
#pragma unroll
  for (int q = 0; q < 8; ++q) {
    const int y = y0 + (q >> 2);
    const int col = (q & 3) * 16 + n;
    const float nz = sn * noise[b * HWSZ + y * 64 + col];
#pragma unroll
    for (int p = 0; p < 4; ++p) {
      const int o0 = G * 256 + wave * 64 + p * 16 + quad * 4;
#pragma unroll
      for (int r = 0; r < 4; ++r) {
        const int o = o0 + r;
        float v = fmaf(acc[p][q][r], demod[b * CC + o], nz + bias[o]);
        out[((size_t)(b * CC + o)) * HWSZ + y * 64 + col] =
            v > 0.f ? v : 0.2f * v;
      }
    }
  }
}

extern "C" void kernel_launch(void* const* d_in, const int* in_sizes, int n_in,
                              void* d_out, int out_size, void* d_ws, size_t ws_size,
                              hipStream_t stream) {
  const float* x     = (const float*)d_in[0];
  const float* w     = (const float*)d_in[1];
  const float* noise = (const float*)d_in[2];
  const float* cw    = (const float*)d_in[3];
  const float* sw    = (const float*)d_in[4];
  const float* sbias = (const float*)d_in[5];
  const float* bias  = (const float*)d_in[6];
  const float* sn    = (const float*)d_in[7];
  float* out = (float*)d_out;

  float* alpha = (float*)d_ws;                        // 4096 f
  float* demod = alpha + BB * CC;                     // 4096 f
  float* wsq   = demod + BB * CC;                     // 262144 f
  short* wfrag = (short*)(wsq + CC * CC);             // 9*16*32*64*8 = 2359296 bf16
  short* xT    = wfrag + (size_t)9 * 16 * 32 * 64 * 8;  // 8*64*66*66*8 bf16

  prepA_kernel<<<dim3(1024 + 512), 256, 0, stream>>>(
      w, sw, sbias, alpha, cw, wfrag, wsq);
  prepB_kernel<<<dim3(1024 + 66 * 16 * BB), 256, 0, stream>>>(
      alpha, wsq, demod, x, xT);
  conv_kernel<<<dim3(32, 2, BB), 256, 0, stream>>>(
      xT, wfrag, noise, bias, sn, demod, out);
}

// Round 8
// 244.664 us; speedup vs baseline: 1.1756x; 1.0150x over previous
//
#include <hip/hip_runtime.h>

// StyleBlock B=8, C=512, H=W=64, K=3 — bf16 MFMA implicit-GEMM conv, round 13.
// Diagnosis (r6-r12 data): conv is bound by the A-fragment L2 stream — 4.6 MB
// per CU per dispatch, oversubscribing the CU memory port ~3.3x per tap
// window. Barrier/pipeline micro-structure is second-order (r9 dbuf neutral,
// r10 regressed, stage expose only ~1.8 us total).
// vs round 6/12 conv:
//  - Block tile 256o x 256px (4 rows), 512 thr = 8 waves (4 o-slices x 2
//    row-pairs), 256 blocks = 1/CU -> per-CU A-traffic HALVES; row-pair wave
//    duos read identical af addresses -> per-tap 16KB A-slab L1-resident.
//  - LDS 2 x [kc8][r6][c66] chunks = 2 x 50688 B, double-buffered, ONE
//    __syncthreads per ib; stage(ib+1) issued inside compute at tap 1 and
//    retired by later af-waits (in-order vmcnt) — no explicit drains.
//  - Per-wave compute identical to r6 (acc[4][8], per-tap af[4]/bf[8],
//    setprio cluster) -> numerics bitwise-identical.
// prepA/prepB = round-12 verbatim.

#define CC 512
#define BB 8
#define HWSZ 4096

#define C_STYLE 0.04419417382415922f   // 1/sqrt(512)
#define C_CONV  0.014731391274719739f  // 1/sqrt(512*9)

typedef __attribute__((ext_vector_type(8))) short bf16x8;
typedef __attribute__((ext_vector_type(4))) float f32x4;

static __device__ __forceinline__ short f2bf(float f) {
  unsigned u = __float_as_uint(f);
  unsigned r = (u + 0x7fffu + ((u >> 16) & 1u)) >> 16;  // RNE
  return (short)r;
}

static __device__ __forceinline__ void load_lds_16(const void* g, void* l) {
  __builtin_amdgcn_global_load_lds(
      (const __attribute__((address_space(1))) unsigned int*)g,
      (__attribute__((address_space(3))) unsigned int*)l, 16, 0, 0);
}

// ---------------- prep A ----------------
// blocks 0..1023:   style_alpha — wave per (b,j)
// blocks 1024..1535: wprep LDS-transpose — block per (ob 32, ib32 16) tile
__global__ __launch_bounds__(256) void prepA_kernel(
    const float* __restrict__ w,
    const float* __restrict__ sw,
    const float* __restrict__ sbias,
    float* __restrict__ alpha,
    const float* __restrict__ cw,
    short* __restrict__ wfrag,
    float* __restrict__ wsq) {
  __shared__ float lds[16][288];             // used by wprep branch only
  if (blockIdx.x < 1024) {
    int wv = (blockIdx.x * blockDim.x + threadIdx.x) >> 6;  // [0, B*C)
    int lane = threadIdx.x & 63;
    int b = wv >> 9;
    int j = wv & 511;
    float acc = 0.f;
    const float* wr = w + b * CC;
    const float* sr = sw + (size_t)j * CC;
#pragma unroll
    for (int k = 0; k < CC; k += 64) acc = fmaf(wr[k + lane], sr[k + lane], acc);
#pragma unroll
    for (int off = 32; off > 0; off >>= 1) acc += __shfl_down(acc, off);
    if (lane == 0) alpha[wv] = C_CONV * fmaf(C_STYLE, acc, sbias[j]);
  } else {
    const int bid = blockIdx.x - 1024;       // 0..511
    const int ob = bid & 31;
    const int ib32 = bid >> 5;               // 0..15
    const int tid = threadIdx.x;
    const int o0 = ob * 16;
    const float* src = cw + (size_t)o0 * 4608 + ib32 * 288;
#pragma unroll
    for (int k = 0; k < 18; ++k) {
      int idx = k * 256 + tid;
      int row = idx / 288;
      int col = idx - row * 288;
      lds[row][col] = src[(size_t)row * 4608 + col];
    }
    __syncthreads();
#pragma unroll
    for (int pp = 0; pp < 2; ++pp) {
      int p = pp * 256 + tid;
      int row = p >> 5;
      int il = p & 31;
      float s = 0.f;
#pragma unroll
      for (int t9 = 0; t9 < 9; ++t9) {
        float v = lds[row][il * 9 + t9];
        s = fmaf(v, v, s);
      }
      wsq[(size_t)(o0 + row) * 512 + ib32 * 32 + il] = s;
    }
    const int lane = tid >> 2;               // 0..63
    const int jj = (tid & 3) * 2;            // 0,2,4,6
    const int row = lane & 15;
    const int ilb = ((lane >> 4) & 3) * 8 + jj;
    short* dst = wfrag + ((size_t)ib32 * 32 + ob) * 512 + tid * 2;
#pragma unroll
    for (int t9 = 0; t9 < 9; ++t9) {
      short2 v;
      v.x = f2bf(lds[row][ilb * 9 + t9]);
      v.y = f2bf(lds[row][(ilb + 1) * 9 + t9]);
      *(short2*)(dst + (size_t)t9 * 16 * 32 * 512) = v;
    }
  }
}

// ---------------- prep B: demod (blocks 0..1023) || xprep (1024..10471)
__global__ void prepB_kernel(const float* __restrict__ alpha,
                             const float* __restrict__ wsq,
                             float* __restrict__ demod,
                             const float* __restrict__ x,
                             short* __restrict__ xT) {
  if (blockIdx.x < 1024) {
    int wv = (blockIdx.x * blockDim.x + threadIdx.x) >> 6;  // [0, B*C)
    int lane = threadIdx.x & 63;
    int b = wv >> 9;
    int o = wv & 511;
    const float* ar = alpha + b * CC;
    const float* qr = wsq + (size_t)o * CC;
    float s = 0.f;
#pragma unroll
    for (int i = 0; i < CC; i += 64) {
      float a = ar[i + lane];
      s = fmaf(a * a, qr[i + lane], s);
    }
#pragma unroll
    for (int off = 32; off > 0; off >>= 1) s += __shfl_down(s, off);
    if (lane == 0) {
      s += 1e-8f;
      float r = rsqrtf(s);
      r = r * fmaf(-0.5f * s * r, r, 1.5f);
      demod[wv] = r;
    }
  } else {
    const int id = blockIdx.x - 1024;       // (py,icg,b): py fastest
    const int py = id % 66;                 // 0..65
    const int rem = id / 66;
    const int icg = rem & 15;
    const int b = rem >> 4;
    const int ic = icg * 4 + (threadIdx.x >> 6);
    const int px = threadIdx.x & 63;
    bf16x8 v = (bf16x8){0, 0, 0, 0, 0, 0, 0, 0};
    if (py >= 1 && py <= 64) {
      const float* xp =
          x + (((size_t)b * CC + ic * 8) * HWSZ + (py - 1) * 64 + px);
      const float* al = alpha + b * CC + ic * 8;
#pragma unroll
      for (int j = 0; j < 8; ++j) v[j] = f2bf(xp[(size_t)j * HWSZ] * al[j]);
    }
    short* row = xT + (((size_t)(b * 64 + ic) * 66 + py) * 66) * 8;
    *(bf16x8*)(row + (px + 1) * 8) = v;
    bf16x8 z = (bf16x8){0, 0, 0, 0, 0, 0, 0, 0};
    if (px == 0) *(bf16x8*)(row) = z;
    if (px == 63) *(bf16x8*)(row + 65 * 8) = z;
  }
}

// ---------------- conv: MFMA implicit GEMM ----------------
// grid 256 blocks (1/CU), 512 threads = 8 waves = 4 o-slices x 2 row-pairs.
// Block tile: 256 o x (4 rows x 64 px). K-loop: 8 ibs of 64 i.
// LDS: 2 x chunks [kc 8][r 6][c 66] x 16B = 2 x 50688 B (double-buffered).
// Swizzle: XCD = lin%8; G = XCD parity (L2-resident 2.36 MB wfrag half).
#define NCHUNK6 3168
__global__ __launch_bounds__(512, 2) void conv_kernel(
    const short* __restrict__ xT,
    const short* __restrict__ wfrag,
    const float* __restrict__ noise,
    const float* __restrict__ bias,
    const float* __restrict__ scale_noise,
    const float* __restrict__ demod,
    float* __restrict__ out) {
  __shared__ __align__(16) short xs[2 * NCHUNK6 * 8];

  const int lin = blockIdx.x + 32 * blockIdx.y;
  const int xcd = lin & 7;                  // assumed hw XCD = lin % 8
  const int j = lin >> 3;                   // 0..31, per-XCD block sequence
  const int G = xcd & 1;                    // 256-o group, constant per XCD
  const int b = (xcd >> 1) + 4 * (j & 1);   // 2 b-values per XCD
  const int y0 = (j >> 1) * 4;              // first output row (0,4,...,60)
  const int tid = threadIdx.x;
  const int lane = tid & 63;
  const int wave = tid >> 6;                // 0..7
  const int ow = wave >> 1;                 // o-slice: o in [G*256+ow*64, +64)
  const int pw = wave & 1;                  // row-pair: rows y0+pw*2 .. +2
  const int n = lane & 15;
  const int quad = lane >> 4;

  f32x4 acc[4][8];                          // [p (16-o frag)][q (row*4+colblk)]
#pragma unroll
  for (int p = 0; p < 4; ++p)
#pragma unroll
    for (int q = 0; q < 8; ++q) acc[p][q] = (f32x4){0.f, 0.f, 0.f, 0.f};

  // staging descriptors: chunk cid = (kc*6 + r)*66 + c  ->  global chunk
  // g = ((b*64 + ib*8 + kc)*66 + (y0+r))*66 + c ; per-ib advance 8*66*66
  const char* xTb = (const char*)xT;
  unsigned goff[7];
#pragma unroll
  for (int it = 0; it < 7; ++it) {
    int cid = tid + it * 512;
    int kc = cid / 396;
    int rem = cid - kc * 396;
    int r = rem / 66;
    int c = rem - r * 66;
    goff[it] = (unsigned)((((b * 64 + kc) * 66 + (y0 + r)) * 66 + c) * 16);
  }

  // A base for this wave's 64-o slice: ob = G*16 + ow*4 + p
  const short* wf0 = wfrag + ((size_t)((G * 16 + ow * 4) * 64 + lane)) * 8;

  // prologue: stage tile 0 into buffer half 0
#pragma unroll
  for (int it = 0; it < 7; ++it) {
    int cid = tid + it * 512;
    if (cid < NCHUNK6) load_lds_16(xTb + goff[it], xs + (size_t)cid * 8);
    goff[it] += 8 * 66 * 66 * 16;
  }

  for (int ib = 0; ib < 8; ++ib) {
    // At this barrier: all waves done reading buf[(ib&1)^1] (stage target),
    // and stage(->buf[ib&1]) already retired via prior af-waits (in-order
    // vmcnt); syncthreads' implicit vmcnt(0) is cheap (af tail only).
    __syncthreads();
    const short* cxs = xs + (size_t)(ib & 1) * NCHUNK6 * 8;

#pragma unroll
    for (int kstep = 0; kstep < 2; ++kstep) {
      const int ib32 = ib * 2 + kstep;
#pragma unroll
      for (int t = 0; t < 9; ++t) {
        const int dy = t / 3 - 1;
        const int dx = t % 3 - 1;
        const short* wp = wf0 + (size_t)(t * 16 + ib32) * 16384;
        bf16x8 af[4];
#pragma unroll
        for (int p = 0; p < 4; ++p)
          af[p] = *(const bf16x8*)(wp + p * 512);
        // stage next ib early in compute: issued after tap-0/1 af loads, so
        // later taps' af-waits retire it under ~16 taps of MFMA cover.
        if (kstep == 0 && t == 1 && ib < 7) {
#pragma unroll
          for (int it = 0; it < 7; ++it) {
            int cid = tid + it * 512;
            if (cid < NCHUNK6)
              load_lds_16(xTb + goff[it],
                          xs + (size_t)(((ib & 1) ^ 1) * NCHUNK6 + cid) * 8);
            goff[it] += 8 * 66 * 66 * 16;
          }
        }
        const int row = pw * 2 + dy + 1;     // 0..5
        const short* bp =
            cxs + (((kstep * 4 + quad) * 6 + row) * 66 + 1 + n + dx) * 8;
        bf16x8 bf[8];
#pragma unroll
        for (int q = 0; q < 8; ++q)
          bf[q] = *(const bf16x8*)(bp + ((q >> 2) * 66 + (q & 3) * 16) * 8);
        __builtin_amdgcn_s_setprio(1);
#pragma unroll
        for (int p = 0; p < 4; ++p)
#pragma unroll
          for (int q = 0; q < 8; ++q)
            acc[p][q] = __builtin_amdgcn_mfma_f32_16x16x32_bf16(
                af[p], bf[q], acc[p][q], 0, 0, 0);
        __builtin_amdgcn_s_setprio(0);
      }
    }
  }

  // epilogue: demod, noise, bias, leaky
  const float sn = scale_noise[0];
#pragma unroll
  for (int q = 0; q < 8; ++q) {
    const int y = y0 + pw * 2 + (q >> 2);
    const int col = (q & 3) * 16 + n;
    const float nz = sn * noise[b * HWSZ + y * 64 + col];
#pragma unroll
    for (int p = 0; p < 4; ++p) {
      const int o0 = G * 256 + ow * 64 + p * 16 + quad * 4;
#pragma unroll
      for (int r = 0; r < 4; ++r) {
        const int o = o0 + r;
        float v = fmaf(acc[p][q][r], demod[b * CC + o], nz + bias[o]);
        out[((size_t)(b * CC + o)) * HWSZ + y * 64 + col] =
            v > 0.f ? v : 0.2f * v;
      }
    }
  }
}

extern "C" void kernel_launch(void* const* d_in, const int* in_sizes, int n_in,
                              void* d_out, int out_size, void* d_ws, size_t ws_size,
                              hipStream_t stream) {
  const float* x     = (const float*)d_in[0];
  const float* w     = (const float*)d_in[1];
  const float* noise = (const float*)d_in[2];
  const float* cw    = (const float*)d_in[3];
  const float* sw    = (const float*)d_in[4];
  const float* sbias = (const float*)d_in[5];
  const float* bias  = (const float*)d_in[6];
  const float* sn    = (const float*)d_in[7];
  float* out = (float*)d_out;

  float* alpha = (float*)d_ws;                        // 4096 f
  float* demod = alpha + BB * CC;                     // 4096 f
  float* wsq   = demod + BB * CC;                     // 262144 f
  short* wfrag = (short*)(wsq + CC * CC);             // 9*16*32*64*8 = 2359296 bf16
  short* xT    = wfrag + (size_t)9 * 16 * 32 * 64 * 8;  // 8*64*66*66*8 bf16

  prepA_kernel<<<dim3(1024 + 512), 256, 0, stream>>>(
      w, sw, sbias, alpha, cw, wfrag, wsq);
  prepB_kernel<<<dim3(1024 + 66 * 16 * BB), 256, 0, stream>>>(
      alpha, wsq, demod, x, xT);
  conv_kernel<<<dim3(32, 8), 512, 0, stream>>>(
      xT, wfrag, noise, bias, sn, demod, out);
}